// Round 8
// baseline (161.909 us; speedup 1.0000x reference)
//
#include <hip/hip_runtime.h>

#define BLK 512
#define MT 32            // mfma tile edge
#define IA 2             // A-frags per wave
#define IB 512           // rows per block = 8 waves * 32 * IA
#define TJQ 512          // q points per LDS chunk
#define SJ 4             // j-slices per (dir,b) -> 512 blocks, one dispatch round
#define NBLK 512         // total blocks (grid 32*4*4) — counter handshake uses this

typedef __attribute__((ext_vector_type(8))) short short8;
typedef __attribute__((ext_vector_type(16))) float f32x16;

__device__ __forceinline__ unsigned int fmap(float f) {
  unsigned int b = __float_as_uint(f);
  return (b & 0x80000000u) ? ~b : (b | 0x80000000u);
}
__device__ __forceinline__ float funmap(unsigned int u) {
  return __uint_as_float((u & 0x80000000u) ? (u ^ 0x80000000u) : ~u);
}
__device__ __forceinline__ unsigned short f2bf(float f) {
  unsigned int u = __float_as_uint(f);
  u += 0x7FFFu + ((u >> 16) & 1u);
  return (unsigned short)(u >> 16);
}
__device__ __forceinline__ float bf2f(unsigned short h) {
  return __uint_as_float(((unsigned int)h) << 16);
}
__device__ __forceinline__ unsigned int pk(unsigned short a, unsigned short b) {
  return (unsigned int)a | ((unsigned int)b << 16);
}

union FragU { uint4 u; short8 s; };

// Two MFMAs into VGPR destinations ("=&v" on the gfx950 unified file).
// s_nop 7,7,1 = 18 cyc covers MFMA D-write -> VALU-read (validated R11,
// absmax margin 0). History: R13 pipelining, R14/R15 occupancy, R16 LDS
// prefetch (neutral), R17 barrier-free, R19 symmetric-one-pass — none beat
// this structure. R19 post-mortem: the duplicated transposed MFMA pass IS
// the cheapest col-min (matrix pipe has idle headroom; register col-trees
// cost more VALU than they save). Hot loop below = the 42.5us validated form.
#define MFMA2(d0, d1, a, b0, b1, c)                                    \
  asm("v_mfma_f32_32x32x16_bf16 %0, %2, %3, %5\n\t"                    \
      "v_mfma_f32_32x32x16_bf16 %1, %2, %4, %5\n\t"                    \
      "s_nop 7\n\t"                                                    \
      "s_nop 7\n\t"                                                    \
      "s_nop 1"                                                        \
      : "=&v"(d0), "=&v"(d1)                                           \
      : "v"(a), "v"(b0), "v"(b1), "v"(c))

// v_min3 with ALL operands pinned to arch VGPRs (R11: prevents AGPR
// allocation of run0/run1 and the a<->v copy tax).
#define MIN3(acc, x, y)                                                \
  asm("v_min3_f32 %0, %0, %1, %2" : "+v"(acc) : "v"(x), "v"(y))

// D_ij = |q_j|^2 - 2 p_i.q_j via split-bf16-compensated MFMA (k-slot layout
// verified R5-R11, absmax margin 0).
// R20: single-kernel fusion. Across R12-R19 the total-minus-cl_mfma tail was
// 54±2us and unmoved by memset removal / reduce restructuring / 3->2
// dispatches. The untested kernel-side lever: eliminate the second KERNEL
// node. Last-block-done pattern: after the epilogue's device-scope atomicMin
// (m20: global atomics are device-scope), release fence + counter; the 512th
// block acquire-fences and reduces um (256KB coalesced) to *out directly.
// Counter sits at ws+256KB, covered by the same 0xFF memset: init
// 0xFFFFFFFF -> atomicAdd returns 0xFFFFFFFF,0,...,510; last block sees
// old==NBLK-2. Graph replay re-runs the memset, so the handshake resets
// every iteration (re-poison safe).
__global__ __launch_bounds__(BLK, 4) void cl_mfma(
    const float* __restrict__ A, const float* __restrict__ Bp,
    unsigned int* __restrict__ umin, unsigned int* __restrict__ cnt,
    float* __restrict__ outp, int N, int jslice, int Bn) {
  __shared__ uint4 sA[2][IB];   // A-vec halves [g][row]
  __shared__ uint4 sB[2][TJQ];  // B-vec halves [g][point]
  __shared__ float sNP[IB];     // |p|^2 per row

  const int zi = blockIdx.z;
  const int dir = zi / Bn;
  const int b = zi - dir * Bn;
  const float* __restrict__ P = dir ? Bp : A;
  const float* __restrict__ Q = dir ? A : Bp;
  unsigned int* __restrict__ um = umin + ((size_t)dir * Bn + b) * N;

  const int t = threadIdx.x;
  const int ib0 = blockIdx.x * IB;
  const int jbase = blockIdx.y * jslice;
  const size_t boff = (size_t)b * 3 * N;
  const unsigned short one = 0x3F80u;  // bf16(1.0)

  // ---- stage A-vectors + |p|^2 (once) ----
  {
    int i = ib0 + t;
    float x = P[boff + i], y = P[boff + N + i], zz = P[boff + 2 * N + i];
    float ax = -2.f * x, ay = -2.f * y, az = -2.f * zz;
    unsigned short hx = f2bf(ax), hy = f2bf(ay), hz = f2bf(az);
    unsigned short lx = f2bf(ax - bf2f(hx)), ly = f2bf(ay - bf2f(hy)),
                   lz = f2bf(az - bf2f(hz));
    sA[0][t] = make_uint4(pk(hx, hy), pk(hz, lx), pk(ly, lz), pk(hx, hy));
    sA[1][t] = make_uint4(pk(hz, lx), pk(ly, lz), pk(one, one), pk(one, 0));
    sNP[t] = fmaf(zz, zz, fmaf(y, y, x * x));
  }
  __syncthreads();

  const int w = t >> 6, l = t & 63, m = l & 31, g = l >> 5;
  FragU a0u, a1u;
  a0u.u = sA[g][w * (MT * IA) + m];        // rows w*64 + 0..31
  a1u.u = sA[g][w * (MT * IA) + MT + m];   // rows w*64 + 32..63
  const short8 af0 = a0u.s, af1 = a1u.s;
  const uint4* __restrict__ sBg = sB[g];

  float run0[16], run1[16];
  f32x16 zc;
#pragma unroll
  for (int r = 0; r < 16; ++r) { run0[r] = 3.0e38f; run1[r] = 3.0e38f; zc[r] = 0.0f; }

  const int nch = jslice / TJQ;  // 8
  float qx = Q[boff + jbase + t];
  float qy = Q[boff + N + jbase + t];
  float qz = Q[boff + 2 * N + jbase + t];

  for (int ch = 0; ch < nch; ++ch) {
    unsigned short hx = f2bf(qx), hy = f2bf(qy), hz = f2bf(qz);
    unsigned short lx = f2bf(qx - bf2f(hx)), ly = f2bf(qy - bf2f(hy)),
                   lz = f2bf(qz - bf2f(hz));
    float nq = fmaf(qz, qz, fmaf(qy, qy, qx * qx));
    unsigned short nh = f2bf(nq);
    float r1 = nq - bf2f(nh);
    unsigned short nm = f2bf(r1);
    unsigned short nl = f2bf(r1 - bf2f(nm));
    uint4 b0s = make_uint4(pk(hx, hy), pk(hz, hx), pk(hy, hz), pk(lx, ly));
    uint4 b1s = make_uint4(pk(lz, lx), pk(ly, lz), pk(nh, nm), pk(nl, 0));

    __syncthreads();  // previous chunk fully consumed
    sB[0][t] = b0s;
    sB[1][t] = b1s;
    {  // prefetch next chunk's q
      int jn = (ch + 1 < nch) ? (jbase + (ch + 1) * TJQ + t) : (jbase + t);
      qx = Q[boff + jn];
      qy = Q[boff + N + jn];
      qz = Q[boff + 2 * N + jn];
    }
    __syncthreads();

    // 1-pair register double-buffer (R16; neutral but validated).
    FragU ba, bb, na, nb;
    ba.u = sBg[m];
    bb.u = sBg[MT + m];
    na = ba; nb = bb;
#pragma unroll
    for (int jt = 0; jt < TJQ / MT; jt += 2) {
      if (jt + 2 < TJQ / MT) {
        na.u = sBg[(jt + 2) * MT + m];
        nb.u = sBg[(jt + 3) * MT + m];
      }
      f32x16 d0, d1;
      MFMA2(d0, d1, af0, ba.s, bb.s, zc);
#pragma unroll
      for (int r = 0; r < 16; ++r) MIN3(run0[r], d0[r], d1[r]);
      f32x16 d2, d3;
      MFMA2(d2, d3, af1, ba.s, bb.s, zc);
#pragma unroll
      for (int r = 0; r < 16; ++r) MIN3(run1[r], d2[r], d3[r]);
      ba = na; bb = nb;
    }
  }

  // ---- epilogue: min across 32 cols, add |p|^2, atomicMin ----
  // C/D layout (m74/m101): col=lane&31, row=(reg&3)+8*(reg>>2)+4*(lane>>5)
#pragma unroll
  for (int r = 0; r < 16; ++r) {
    float v0 = run0[r], v1 = run1[r];
#pragma unroll
    for (int sh = 1; sh <= 16; sh <<= 1) {
      v0 = fminf(v0, __shfl_xor(v0, sh));
      v1 = fminf(v1, __shfl_xor(v1, sh));
    }
    if (m == 0) {
      int row = (r & 3) + 8 * (r >> 2) + 4 * g;
      int il0 = w * (MT * IA) + row;
      int il1 = il0 + MT;
      atomicMin(&um[ib0 + il0], fmap(v0 + sNP[il0]));
      atomicMin(&um[ib0 + il1], fmap(v1 + sNP[il1]));
    }
  }

  // ---- R20 fused tail: last block reduces um -> *out ----
  __threadfence();  // release: our atomicMin results visible device-wide
  __shared__ int slast;
  if (t == 0) slast = (atomicAdd(cnt, 1u) == (unsigned int)(NBLK - 2));
  __syncthreads();
  if (slast) {
    __threadfence();  // acquire: invalidate caches before re-reading um
    const int total = 2 * Bn * N;          // 65536 entries, 256 KB
    const uint4* __restrict__ u4 = (const uint4*)umin;
    double s = 0.0;
    for (int i = t; i < total / 4; i += BLK) {  // coalesced, 32 iters/thread
      uint4 v = u4[i];
      s += (double)funmap(v.x) + (double)funmap(v.y) +
           (double)funmap(v.z) + (double)funmap(v.w);
    }
    for (int off = 32; off > 0; off >>= 1) s += __shfl_down(s, off, 64);
    __shared__ double sw[8];
    if (l == 0) sw[w] = s;
    __syncthreads();
    if (t == 0) {
      double tot = 0.0;
#pragma unroll
      for (int i = 0; i < 8; ++i) tot += sw[i];
      *outp = (float)(tot / (double)total);  // single writer, no atomic
    }
  }
}

extern "C" void kernel_launch(void* const* d_in, const int* in_sizes, int n_in,
                              void* d_out, int out_size, void* d_ws, size_t ws_size,
                              hipStream_t stream) {
  const float* in_pc = (const float*)d_in[0];
  const float* tgt_pc = (const float*)d_in[1];
  const int B = 2, N = 16384;
  float* out = (float*)d_out;

  // workspace: um [2][B][N] uints (256 KB) + counter (4 B), one 0xFF memset
  // covers both (counter init 0xFFFFFFFF -> last atomicAdd returns NBLK-2).
  unsigned int* u = (unsigned int*)d_ws;
  unsigned int* cnt = u + (size_t)2 * B * N;
  hipMemsetAsync(u, 0xFF, (size_t)2 * B * N * sizeof(unsigned int) + 4, stream);

  const int jslice = N / SJ;             // 4096
  dim3 grid(N / IB, SJ, 2 * B);          // (32,4,4) = 512 blocks x 512 thr
  cl_mfma<<<grid, dim3(BLK), 0, stream>>>(in_pc, tgt_pc, u, cnt, out, N,
                                          jslice, B);
}

// Round 11
// 96.913 us; speedup vs baseline: 1.6707x; 1.6707x over previous
//
#include <hip/hip_runtime.h>

#define BLK 512
#define MT 32            // mfma tile edge
#define IA 2             // A-frags per wave
#define IB 512           // rows per block = 8 waves * 32 * IA
#define TJQ 512          // q points per LDS chunk
#define SJ 4             // j-slices per (dir,b) -> 512 blocks, one dispatch round

typedef __attribute__((ext_vector_type(8))) short short8;
typedef __attribute__((ext_vector_type(16))) float f32x16;

__device__ __forceinline__ unsigned int fmap(float f) {
  unsigned int b = __float_as_uint(f);
  return (b & 0x80000000u) ? ~b : (b | 0x80000000u);
}
__device__ __forceinline__ float funmap(unsigned int u) {
  return __uint_as_float((u & 0x80000000u) ? (u ^ 0x80000000u) : ~u);
}
__device__ __forceinline__ unsigned short f2bf(float f) {
  unsigned int u = __float_as_uint(f);
  u += 0x7FFFu + ((u >> 16) & 1u);
  return (unsigned short)(u >> 16);
}
__device__ __forceinline__ float bf2f(unsigned short h) {
  return __uint_as_float(((unsigned int)h) << 16);
}
__device__ __forceinline__ unsigned int pk(unsigned short a, unsigned short b) {
  return (unsigned int)a | ((unsigned int)b << 16);
}

union FragU { uint4 u; short8 s; };

// Two MFMAs into VGPR destinations ("=&v" on the gfx950 unified file).
// s_nop 7,7,1 = 18 cyc covers MFMA D-write -> VALU-read (validated R11,
// absmax margin 0). Ledger: R13 pipelining/fences (-29%), R14 8-waves
// (spill, -30x), R15 4 barrier domains (-11%), R16 LDS double-buffer
// (null), R17 barrier-free whole-slice (-43%), R19 symmetric one-pass
// (col-VALU ate the MFMA halving), R20 fused tail (per-wave threadfence =
// L2 writeback per wave, -2.5x), R21 raw-barrier staging (2x container
// failure — s_barrier builtin is not a memory fence; without
// sched_barrier(0) after each, LDS ops can cross the HW barrier; pattern
// abandoned). This is the Round-4 binary: best measured total 97.38us.
#define MFMA2(d0, d1, a, b0, b1, c)                                    \
  asm("v_mfma_f32_32x32x16_bf16 %0, %2, %3, %5\n\t"                    \
      "v_mfma_f32_32x32x16_bf16 %1, %2, %4, %5\n\t"                    \
      "s_nop 7\n\t"                                                    \
      "s_nop 7\n\t"                                                    \
      "s_nop 1"                                                        \
      : "=&v"(d0), "=&v"(d1)                                           \
      : "v"(a), "v"(b0), "v"(b1), "v"(c))

// v_min3 with ALL operands pinned to arch VGPRs (R11: prevents AGPR
// allocation of run0/run1 and the a<->v copy tax).
#define MIN3(acc, x, y)                                                \
  asm("v_min3_f32 %0, %0, %1, %2" : "+v"(acc) : "v"(x), "v"(y))

// D_ij = |q_j|^2 - 2 p_i.q_j via split-bf16-compensated MFMA (k-slot layout
// verified R5-R11, absmax margin 0). Structure: 42.5us kernel floor,
// invariant across 8 structural experiments; total-minus-kernel tail
// ~54us proven harness-fixed (linear across R12-R20).
__global__ __launch_bounds__(BLK, 4) void cl_mfma(
    const float* __restrict__ A, const float* __restrict__ Bp,
    unsigned int* __restrict__ umin, float* __restrict__ outp,
    int N, int jslice, int Bn) {
  __shared__ uint4 sA[2][IB];   // A-vec halves [g][row]
  __shared__ uint4 sB[2][TJQ];  // B-vec halves [g][point]
  __shared__ float sNP[IB];     // |p|^2 per row

  const int zi = blockIdx.z;
  const int dir = zi / Bn;
  const int b = zi - dir * Bn;
  const float* __restrict__ P = dir ? Bp : A;
  const float* __restrict__ Q = dir ? A : Bp;
  unsigned int* __restrict__ um = umin + ((size_t)dir * Bn + b) * N;

  const int t = threadIdx.x;

  // zero the scalar output here (stream order puts cl_reduce after all
  // cl_mfma blocks) — saves the out-memset launch node. (validated R16)
  if (blockIdx.x == 0 && blockIdx.y == 0 && blockIdx.z == 0 && t == 0)
    *outp = 0.0f;

  const int ib0 = blockIdx.x * IB;
  const int jbase = blockIdx.y * jslice;
  const size_t boff = (size_t)b * 3 * N;
  const unsigned short one = 0x3F80u;  // bf16(1.0)

  // ---- stage A-vectors + |p|^2 (once) ----
  {
    int i = ib0 + t;
    float x = P[boff + i], y = P[boff + N + i], zz = P[boff + 2 * N + i];
    float ax = -2.f * x, ay = -2.f * y, az = -2.f * zz;
    unsigned short hx = f2bf(ax), hy = f2bf(ay), hz = f2bf(az);
    unsigned short lx = f2bf(ax - bf2f(hx)), ly = f2bf(ay - bf2f(hy)),
                   lz = f2bf(az - bf2f(hz));
    sA[0][t] = make_uint4(pk(hx, hy), pk(hz, lx), pk(ly, lz), pk(hx, hy));
    sA[1][t] = make_uint4(pk(hz, lx), pk(ly, lz), pk(one, one), pk(one, 0));
    sNP[t] = fmaf(zz, zz, fmaf(y, y, x * x));
  }
  __syncthreads();

  const int w = t >> 6, l = t & 63, m = l & 31, g = l >> 5;
  FragU a0u, a1u;
  a0u.u = sA[g][w * (MT * IA) + m];        // rows w*64 + 0..31
  a1u.u = sA[g][w * (MT * IA) + MT + m];   // rows w*64 + 32..63
  const short8 af0 = a0u.s, af1 = a1u.s;
  const uint4* __restrict__ sBg = sB[g];

  float run0[16], run1[16];
  f32x16 zc;
#pragma unroll
  for (int r = 0; r < 16; ++r) { run0[r] = 3.0e38f; run1[r] = 3.0e38f; zc[r] = 0.0f; }

  const int nch = jslice / TJQ;  // 8
  float qx = Q[boff + jbase + t];
  float qy = Q[boff + N + jbase + t];
  float qz = Q[boff + 2 * N + jbase + t];

  for (int ch = 0; ch < nch; ++ch) {
    unsigned short hx = f2bf(qx), hy = f2bf(qy), hz = f2bf(qz);
    unsigned short lx = f2bf(qx - bf2f(hx)), ly = f2bf(qy - bf2f(hy)),
                   lz = f2bf(qz - bf2f(hz));
    float nq = fmaf(qz, qz, fmaf(qy, qy, qx * qx));
    unsigned short nh = f2bf(nq);
    float r1 = nq - bf2f(nh);
    unsigned short nm = f2bf(r1);
    unsigned short nl = f2bf(r1 - bf2f(nm));
    uint4 b0s = make_uint4(pk(hx, hy), pk(hz, hx), pk(hy, hz), pk(lx, ly));
    uint4 b1s = make_uint4(pk(lz, lx), pk(ly, lz), pk(nh, nm), pk(nl, 0));

    __syncthreads();  // previous chunk fully consumed
    sB[0][t] = b0s;
    sB[1][t] = b1s;
    {  // prefetch next chunk's q
      int jn = (ch + 1 < nch) ? (jbase + (ch + 1) * TJQ + t) : (jbase + t);
      qx = Q[boff + jn];
      qy = Q[boff + N + jn];
      qz = Q[boff + 2 * N + jn];
    }
    __syncthreads();

    // 1-pair register double-buffer (R16; neutral but validated).
    FragU ba, bb, na, nb;
    ba.u = sBg[m];
    bb.u = sBg[MT + m];
    na = ba; nb = bb;
#pragma unroll
    for (int jt = 0; jt < TJQ / MT; jt += 2) {
      if (jt + 2 < TJQ / MT) {
        na.u = sBg[(jt + 2) * MT + m];
        nb.u = sBg[(jt + 3) * MT + m];
      }
      f32x16 d0, d1;
      MFMA2(d0, d1, af0, ba.s, bb.s, zc);
#pragma unroll
      for (int r = 0; r < 16; ++r) MIN3(run0[r], d0[r], d1[r]);
      f32x16 d2, d3;
      MFMA2(d2, d3, af1, ba.s, bb.s, zc);
#pragma unroll
      for (int r = 0; r < 16; ++r) MIN3(run1[r], d2[r], d3[r]);
      ba = na; bb = nb;
    }
  }

  // ---- epilogue: min across 32 cols, add |p|^2, atomicMin ----
  // C/D layout (m74/m101): col=lane&31, row=(reg&3)+8*(reg>>2)+4*(lane>>5)
#pragma unroll
  for (int r = 0; r < 16; ++r) {
    float v0 = run0[r], v1 = run1[r];
#pragma unroll
    for (int sh = 1; sh <= 16; sh <<= 1) {
      v0 = fminf(v0, __shfl_xor(v0, sh));
      v1 = fminf(v1, __shfl_xor(v1, sh));
    }
    if (m == 0) {
      int row = (r & 3) + 8 * (r >> 2) + 4 * g;
      int il0 = w * (MT * IA) + row;
      int il1 = il0 + MT;
      atomicMin(&um[ib0 + il0], fmap(v0 + sNP[il0]));
      atomicMin(&um[ib0 + il1], fmap(v1 + sNP[il1]));
    }
  }
}

// Parallel final reduce: u holds complete squared distances (256 KB).
__global__ __launch_bounds__(256) void cl_reduce(
    const unsigned int* __restrict__ u, float* __restrict__ out, int total) {
  const int t = threadIdx.x;
  const uint4* __restrict__ u4 = (const uint4*)u;
  const int n4 = total / 4;
  const int gid = blockIdx.x * 256 + t;
  const int gstride = gridDim.x * 256;
  double s = 0.0;
  for (int i = gid; i < n4; i += gstride) {
    uint4 v = u4[i];
    s += (double)funmap(v.x) + (double)funmap(v.y) +
         (double)funmap(v.z) + (double)funmap(v.w);
  }
  for (int off = 32; off > 0; off >>= 1) s += __shfl_down(s, off, 64);
  __shared__ double sw[4];
  if ((t & 63) == 0) sw[t >> 6] = s;
  __syncthreads();
  if (t == 0) {
    double tot = sw[0] + sw[1] + sw[2] + sw[3];
    atomicAdd(out, (float)(tot / (double)total));
  }
}

extern "C" void kernel_launch(void* const* d_in, const int* in_sizes, int n_in,
                              void* d_out, int out_size, void* d_ws, size_t ws_size,
                              hipStream_t stream) {
  const float* in_pc = (const float*)d_in[0];
  const float* tgt_pc = (const float*)d_in[1];
  const int B = 2, N = 16384;
  unsigned int* u = (unsigned int*)d_ws;  // [2][B][N] uints = 256 KB
  float* out = (float*)d_out;

  hipMemsetAsync(u, 0xFF, (size_t)2 * B * N * sizeof(unsigned int), stream);

  const int jslice = N / SJ;             // 4096
  dim3 grid(N / IB, SJ, 2 * B);          // (32,4,4) = 512 blocks x 512 thr
  cl_mfma<<<grid, dim3(BLK), 0, stream>>>(in_pc, tgt_pc, u, out, N, jslice, B);

  const int total = 2 * B * N;
  cl_reduce<<<dim3(16), dim3(256), 0, stream>>>(u, out, total);
}